// Round 5
// baseline (275.647 us; speedup 1.0000x reference)
//
#include <hip/hip_runtime.h>
#include <hip/hip_bf16.h>
#include <stdint.h>

typedef unsigned short u16;
typedef __attribute__((ext_vector_type(8))) short short8_t;
typedef __attribute__((ext_vector_type(4))) float f32x4;

#define D_DIM 512
#define K_CL  256
#define BM    128
#define BK    64
#define NSTEP (D_DIM / BK)   // 8

__device__ __forceinline__ u16 f2bf(float f) {
  union { float f; uint32_t u; } v; v.f = f;
  uint32_t r = v.u + 0x7fffu + ((v.u >> 16) & 1u);  // RNE
  return (u16)(r >> 16);
}

// native RNE converts; compiler emits v_cvt (pairs to cvt_pk where possible)
__device__ __forceinline__ short8_t pack8(const float4& f0, const float4& f1) {
  union { __hip_bfloat16 h[8]; short8_t v; } pk;
  pk.h[0] = __float2bfloat16(f0.x); pk.h[1] = __float2bfloat16(f0.y);
  pk.h[2] = __float2bfloat16(f0.z); pk.h[3] = __float2bfloat16(f0.w);
  pk.h[4] = __float2bfloat16(f1.x); pk.h[5] = __float2bfloat16(f1.y);
  pk.h[6] = __float2bfloat16(f1.z); pk.h[7] = __float2bfloat16(f1.w);
  return pk.v;
}

// prep: clusters fp32 [256][512] -> bf16 cb [256][512] + csq[256] (fp32 norms)
__global__ void prep_kernel(const float* __restrict__ clusters,
                            u16* __restrict__ cb, float* __restrict__ csq) {
  int k = blockIdx.x;
  int t = threadIdx.x;  // 128 threads, 4 floats each
  float4 f = ((const float4*)(clusters + (size_t)k * D_DIM))[t];
  ushort4 u;
  u.x = f2bf(f.x); u.y = f2bf(f.y); u.z = f2bf(f.z); u.w = f2bf(f.w);
  ((ushort4*)(cb + (size_t)k * D_DIM))[t] = u;
  float s = f.x*f.x + f.y*f.y + f.z*f.z + f.w*f.w;
  #pragma unroll
  for (int m = 1; m < 64; m <<= 1) s += __shfl_xor(s, m, 64);
  __shared__ float part[2];
  if ((t & 63) == 0) part[t >> 6] = s;
  __syncthreads();
  if (t == 0) csq[k] = part[0] + part[1];
}

// main: 4 waves/block, each wave owns 32 rows x 256 cols (M-rep 2).
// Issue-early staging: STAGE(next)+A-prefetch issued immediately after the
// barrier so they age a full compute phase before the next barrier's drain.
// B: LDS double-buffer, global_load_lds w=16, linear dest + pre-swizzled
// source + swizzled ds_read (verified R1/R4 scheme). Step loop fully unrolled
// so A-register ping-pong indices are static.
__global__ __launch_bounds__(256, 2)
void cluster_kernel(const float* __restrict__ x,
                    const u16* __restrict__ cb,
                    const float* __restrict__ csq,
                    float* __restrict__ out) {
  __shared__ u16 lB[2 * K_CL * BK];   // 64 KB double buffer

  const int tid  = threadIdx.x;       // 256 threads
  const int lane = tid & 63;
  const int w    = tid >> 6;          // wave 0..3 -> 32-row stripe
  const int l16  = lane & 15;
  const int quad = lane >> 4;
  const int row0 = blockIdx.x * BM;

  // ---- A: lane covers rows (w*32+l16) and (w*32+16+l16), k-slice quad*8 ----
  const float4* xg0 = (const float4*)(x + (size_t)(row0 + w * 32 + l16) * D_DIM + quad * 8);
  const float4* xg1 = xg0 + 16 * (D_DIM / 4);   // +16 rows

  // ---- B staging source (pre-swizzled; dest stays linear) ----
  // dest byte o = i*4096 + tid*16 (i=0..7); row n = o>>7 = (tid>>3) + i*32;
  // in-row kb = (tid&7)*16; swizzled kb' = kb ^ ((n&7)<<4); n&7 invariant in i.
  const int kbp = ((tid & 7) * 16) ^ (((tid >> 3) & 7) * 16);
  const u16* sp = cb + (size_t)(tid >> 3) * D_DIM + (kbp >> 1);

  // ---- swizzled ds_read byte offsets (verified) ----
  const int c3 = (l16 & 3) << 4;
  const int h  = (l16 & 4) << 4;
  const int p  = l16 * 128 + ((quad * 16) ^ c3);
  const int p0 = p + h;           // k32 = 0
  const int p1 = p + (h ^ 64);    // k32 = 1

  f32x4 acc[2][16];
  #pragma unroll
  for (int mi = 0; mi < 2; ++mi)
    #pragma unroll
    for (int i = 0; i < 16; ++i) acc[mi][i] = (f32x4){0.f, 0.f, 0.f, 0.f};

  float4 aR[2][8];

  // ---- prologue: stage step 0 into buf0, load A step 0 ----
  {
    char* dstb = (char*)lB + tid * 16;
    #pragma unroll
    for (int i = 0; i < 8; ++i)
      __builtin_amdgcn_global_load_lds(
          (const __attribute__((address_space(1))) void*)(sp + i * 16384),
          (__attribute__((address_space(3))) void*)(dstb + i * 4096), 16, 0, 0);
  }
  {
    aR[0][0] = xg0[0]; aR[0][1] = xg0[1]; aR[0][2] = xg0[8]; aR[0][3] = xg0[9];
    aR[0][4] = xg1[0]; aR[0][5] = xg1[1]; aR[0][6] = xg1[8]; aR[0][7] = xg1[9];
  }

  float sq0 = 0.f, sq1 = 0.f;

  #pragma unroll
  for (int step = 0; step < NSTEP; ++step) {
    __syncthreads();   // buf[step&1] staged; buf[step&1 ^ 1] free

    // ---- issue next-tile loads FIRST (age a full phase before next drain) ----
    if (step + 1 < NSTEP) {
      const u16* spq = sp + (step + 1) * BK;
      char* dstb = (char*)lB + (((step + 1) & 1) << 15) + tid * 16;
      #pragma unroll
      for (int i = 0; i < 8; ++i)
        __builtin_amdgcn_global_load_lds(
            (const __attribute__((address_space(1))) void*)(spq + i * 16384),
            (__attribute__((address_space(3))) void*)(dstb + i * 4096), 16, 0, 0);
      const float4* g0 = xg0 + (step + 1) * 16;
      const float4* g1 = xg1 + (step + 1) * 16;
      float4* an = aR[(step + 1) & 1];
      an[0] = g0[0]; an[1] = g0[1]; an[2] = g0[8]; an[3] = g0[9];
      an[4] = g1[0]; an[5] = g1[1]; an[6] = g1[8]; an[7] = g1[9];
    }

    // ---- pack current A + ||x||^2 ----
    const float4* a = aR[step & 1];
    sq0 += a[0].x*a[0].x + a[0].y*a[0].y + a[0].z*a[0].z + a[0].w*a[0].w
         + a[1].x*a[1].x + a[1].y*a[1].y + a[1].z*a[1].z + a[1].w*a[1].w
         + a[2].x*a[2].x + a[2].y*a[2].y + a[2].z*a[2].z + a[2].w*a[2].w
         + a[3].x*a[3].x + a[3].y*a[3].y + a[3].z*a[3].z + a[3].w*a[3].w;
    sq1 += a[4].x*a[4].x + a[4].y*a[4].y + a[4].z*a[4].z + a[4].w*a[4].w
         + a[5].x*a[5].x + a[5].y*a[5].y + a[5].z*a[5].z + a[5].w*a[5].w
         + a[6].x*a[6].x + a[6].y*a[6].y + a[6].z*a[6].z + a[6].w*a[6].w
         + a[7].x*a[7].x + a[7].y*a[7].y + a[7].z*a[7].z + a[7].w*a[7].w;
    short8_t aF00 = pack8(a[0], a[1]);   // rows w*32+l16,    k 0..31
    short8_t aF01 = pack8(a[2], a[3]);   //                   k 32..63
    short8_t aF10 = pack8(a[4], a[5]);   // rows w*32+16+l16, k 0..31
    short8_t aF11 = pack8(a[6], a[7]);   //                   k 32..63

    // ---- B frags from swizzled LDS: 32 ds_read_b128 feed 64 MFMAs ----
    const char* pb = (const char*)lB + ((step & 1) << 15);
    #pragma unroll
    for (int ni = 0; ni < 16; ++ni) {
      short8_t b0 = *(const short8_t*)(pb + ni * 2048 + p0);   // k32 = 0
      short8_t b1 = *(const short8_t*)(pb + ni * 2048 + p1);   // k32 = 1
      acc[0][ni] = __builtin_amdgcn_mfma_f32_16x16x32_bf16(aF00, b0, acc[0][ni], 0, 0, 0);
      acc[0][ni] = __builtin_amdgcn_mfma_f32_16x16x32_bf16(aF01, b1, acc[0][ni], 0, 0, 0);
      acc[1][ni] = __builtin_amdgcn_mfma_f32_16x16x32_bf16(aF10, b0, acc[1][ni], 0, 0, 0);
      acc[1][ni] = __builtin_amdgcn_mfma_f32_16x16x32_bf16(aF11, b1, acc[1][ni], 0, 0, 0);
    }
  }

  // ---- epilogue (wave-local, verified) ----
  sq0 += __shfl_xor(sq0, 16, 64); sq0 += __shfl_xor(sq0, 32, 64);
  sq1 += __shfl_xor(sq1, 16, 64); sq1 += __shfl_xor(sq1, 32, 64);
  // C layout: row = mi*16 + quad*4 + v, col = ni*16 + l16
  float xs[2][4];
  #pragma unroll
  for (int v = 0; v < 4; ++v) {
    xs[0][v] = __shfl(sq0, quad * 4 + v, 64);
    xs[1][v] = __shfl(sq1, quad * 4 + v, 64);
  }

  float cs[16];
  #pragma unroll
  for (int ni = 0; ni < 16; ++ni) cs[ni] = csq[ni * 16 + l16];

  #pragma unroll
  for (int mi = 0; mi < 2; ++mi) {
    float rs[4] = {0.f, 0.f, 0.f, 0.f};
    #pragma unroll
    for (int ni = 0; ni < 16; ++ni) {
      #pragma unroll
      for (int v = 0; v < 4; ++v) {
        float d = xs[mi][v] + cs[ni] - 2.0f * acc[mi][ni][v];
        d = fmaxf(d, 0.f);
        float qv = __builtin_amdgcn_rcpf(1.0f + d);   // alpha=1: (1+d^2)^-1
        acc[mi][ni][v] = qv;
        rs[v] += qv;
      }
    }
    #pragma unroll
    for (int v = 0; v < 4; ++v) {
      rs[v] += __shfl_xor(rs[v], 1, 64);
      rs[v] += __shfl_xor(rs[v], 2, 64);
      rs[v] += __shfl_xor(rs[v], 4, 64);
      rs[v] += __shfl_xor(rs[v], 8, 64);
      rs[v] = __builtin_amdgcn_rcpf(rs[v]);
    }
    #pragma unroll
    for (int v = 0; v < 4; ++v) {
      float* orow = out + (size_t)(row0 + w * 32 + mi * 16 + quad * 4 + v) * K_CL;
      #pragma unroll
      for (int ni = 0; ni < 16; ++ni)
        orow[ni * 16 + l16] = acc[mi][ni][v] * rs[v];
    }
  }
}

extern "C" void kernel_launch(void* const* d_in, const int* in_sizes, int n_in,
                              void* d_out, int out_size, void* d_ws, size_t ws_size,
                              hipStream_t stream) {
  const float* x        = (const float*)d_in[0];
  const float* clusters = (const float*)d_in[1];
  float* out = (float*)d_out;
  const int N = in_sizes[0] / D_DIM;   // 65536

  u16*   cb  = (u16*)d_ws;                                    // 256*512*2 = 256 KB
  float* csq = (float*)((char*)d_ws + (size_t)K_CL * D_DIM * sizeof(u16));

  prep_kernel<<<K_CL, 128, 0, stream>>>(clusters, cb, csq);
  cluster_kernel<<<N / BM, 256, 0, stream>>>(x, cb, csq, out);
}

// Round 6
// 232.972 us; speedup vs baseline: 1.1832x; 1.1832x over previous
//
#include <hip/hip_runtime.h>
#include <hip/hip_bf16.h>
#include <stdint.h>

typedef unsigned short u16;
typedef __attribute__((ext_vector_type(8))) short short8_t;
typedef __attribute__((ext_vector_type(4))) float f32x4;
typedef __attribute__((ext_vector_type(4))) unsigned int u32x4;

#define D_DIM 512
#define K_CL  256
#define BM    128
#define BK    64
#define NSTEP 8

__device__ __forceinline__ u16 f2bf(float f) {
  union { float f; uint32_t u; } v; v.f = f;
  uint32_t r = v.u + 0x7fffu + ((v.u >> 16) & 1u);  // RNE
  return (u16)(r >> 16);
}

// native RNE converts; compiler emits v_cvt (pairs where possible)
__device__ __forceinline__ short8_t pack8(const float4& f0, const float4& f1) {
  union { __hip_bfloat16 h[8]; short8_t v; } pk;
  pk.h[0] = __float2bfloat16(f0.x); pk.h[1] = __float2bfloat16(f0.y);
  pk.h[2] = __float2bfloat16(f0.z); pk.h[3] = __float2bfloat16(f0.w);
  pk.h[4] = __float2bfloat16(f1.x); pk.h[5] = __float2bfloat16(f1.y);
  pk.h[6] = __float2bfloat16(f1.z); pk.h[7] = __float2bfloat16(f1.w);
  return pk.v;
}

// prep: clusters fp32 [256][512] -> bf16 cb [256][512] + csq[256] (fp32 norms)
__global__ void prep_kernel(const float* __restrict__ clusters,
                            u16* __restrict__ cb, float* __restrict__ csq) {
  int k = blockIdx.x;
  int t = threadIdx.x;  // 128 threads, 4 floats each
  float4 f = ((const float4*)(clusters + (size_t)k * D_DIM))[t];
  ushort4 u;
  u.x = f2bf(f.x); u.y = f2bf(f.y); u.z = f2bf(f.z); u.w = f2bf(f.w);
  ((ushort4*)(cb + (size_t)k * D_DIM))[t] = u;
  float s = f.x*f.x + f.y*f.y + f.z*f.z + f.w*f.w;
  #pragma unroll
  for (int m = 1; m < 64; m <<= 1) s += __shfl_xor(s, m, 64);
  __shared__ float part[2];
  if ((t & 63) == 0) part[t >> 6] = s;
  __syncthreads();
  if (t == 0) csq[k] = part[0] + part[1];
}

// main: 8 waves/block (512 thr), wave owns 16 rows x 256 cols. 2 blocks/CU.
// B: global -> regs (issued 1 step early) -> swizzled ds_write -> LDS dbuf.
// Barriers are raw s_barrier + lgkmcnt(0) ONLY -- global loads stay in
// flight across them (counted vmcnt inserted by compiler at the use).
__global__ __launch_bounds__(512, 2)
void cluster_kernel(const float* __restrict__ x,
                    const u16* __restrict__ cb,
                    const float* __restrict__ csq,
                    float* __restrict__ out) {
  __shared__ __align__(128) u16 lB[2 * K_CL * BK];   // 64 KB double buffer

  const int tid  = threadIdx.x;       // 512 threads
  const int lane = tid & 63;
  const int w    = tid >> 6;          // wave 0..7 -> 16-row stripe
  const int l16  = lane & 15;
  const int quad = lane >> 4;
  const int row0 = blockIdx.x * BM;

  // ---- A: lane covers row (w*16+l16), k-slice quad*8 (+0/+32) ----
  const float4* xg = (const float4*)(x + (size_t)(row0 + w * 16 + l16) * D_DIM + quad * 8);

  // ---- B staging maps (linear global source; swizzle applied at ds_write) ----
  // chunk i (0..3): row n = i*64 + (tid>>3), in-row 16B slot j = tid&7.
  // LDS dest byte = i*8192 + n%64*128 ... = i*8192 + (tid>>3)*128 + (j*16 ^ ((n&7)<<4))
  const int rgrp  = tid >> 3;         // 0..63
  const int jslot = tid & 7;
  const u16* bsrc = cb + (size_t)rgrp * D_DIM + jslot * 8;       // + i*64*D_DIM + step*64
  const int  dsw  = rgrp * 128 + ((jslot * 16) ^ ((rgrp & 7) << 4));  // + i*8192 + bufsel

  // ---- swizzled ds_read byte offsets (verified R1 math) ----
  const int c3 = (l16 & 3) << 4;
  const int h  = (l16 & 4) << 4;
  const int p  = l16 * 128 + ((quad * 16) ^ c3);
  const int p0 = p + h;           // k32 = 0
  const int p1 = p + (h ^ 64);    // k32 = 1

  f32x4 acc[16];
  #pragma unroll
  for (int i = 0; i < 16; ++i) acc[i] = (f32x4){0.f, 0.f, 0.f, 0.f};

  u32x4 Br[4];
  float4 a0, a1, a2, a3;

  // ---- prologue: B(0)->regs->buf0, A(0)->regs, issue B(1) ----
  #pragma unroll
  for (int i = 0; i < 4; ++i)
    Br[i] = *(const u32x4*)(bsrc + (size_t)i * 64 * D_DIM);
  a0 = xg[0]; a1 = xg[1]; a2 = xg[8]; a3 = xg[9];
  #pragma unroll
  for (int i = 0; i < 4; ++i)
    *(u32x4*)((char*)lB + i * 8192 + dsw) = Br[i];
  #pragma unroll
  for (int i = 0; i < 4; ++i)
    Br[i] = *(const u32x4*)(bsrc + (size_t)i * 64 * D_DIM + 64);   // step 1 slice
  asm volatile("s_waitcnt lgkmcnt(0)" ::: "memory");
  __builtin_amdgcn_s_barrier();
  __builtin_amdgcn_sched_barrier(0);

  float sq = 0.f;

  #pragma unroll
  for (int step = 0; step < NSTEP; ++step) {
    // invariant: buf[step&1] ready; Br holds B(step+1) (in flight, aged ~1 step)

    // ---- ds_write B(step+1) into the other buffer (readers done at last barrier) ----
    if (step + 1 < NSTEP) {
      char* db = (char*)lB + (((step + 1) & 1) << 15) + dsw;
      #pragma unroll
      for (int i = 0; i < 4; ++i)
        *(u32x4*)(db + i * 8192) = Br[i];
    }
    // ---- issue B(step+2) ----
    if (step + 2 < NSTEP) {
      #pragma unroll
      for (int i = 0; i < 4; ++i)
        Br[i] = *(const u32x4*)(bsrc + (size_t)i * 64 * D_DIM + (size_t)(step + 2) * 64);
    }

    // ---- pack current A + ||x||^2 (A loads aged ~1 full step) ----
    sq += a0.x*a0.x + a0.y*a0.y + a0.z*a0.z + a0.w*a0.w
        + a1.x*a1.x + a1.y*a1.y + a1.z*a1.z + a1.w*a1.w
        + a2.x*a2.x + a2.y*a2.y + a2.z*a2.z + a2.w*a2.w
        + a3.x*a3.x + a3.y*a3.y + a3.z*a3.z + a3.w*a3.w;
    short8_t aF0 = pack8(a0, a1);
    short8_t aF1 = pack8(a2, a3);

    // ---- issue A(step+1) ----
    if (step + 1 < NSTEP) {
      const float4* g = xg + (step + 1) * 16;
      a0 = g[0]; a1 = g[1]; a2 = g[8]; a3 = g[9];
    }

    // ---- MFMA phase: 32 swizzled ds_read_b128 feed 32 MFMAs ----
    const char* pb = (const char*)lB + ((step & 1) << 15);
    #pragma unroll
    for (int ni = 0; ni < 16; ++ni) {
      short8_t b0 = *(const short8_t*)(pb + ni * 2048 + p0);   // k32 = 0
      short8_t b1 = *(const short8_t*)(pb + ni * 2048 + p1);   // k32 = 1
      acc[ni] = __builtin_amdgcn_mfma_f32_16x16x32_bf16(aF0, b0, acc[ni], 0, 0, 0);
      acc[ni] = __builtin_amdgcn_mfma_f32_16x16x32_bf16(aF1, b1, acc[ni], 0, 0, 0);
    }

    // ---- light barrier: LDS drain only; global loads stay in flight ----
    if (step + 1 < NSTEP) {
      asm volatile("s_waitcnt lgkmcnt(0)" ::: "memory");
      __builtin_amdgcn_s_barrier();
      __builtin_amdgcn_sched_barrier(0);
    }
  }

  // ---- epilogue (wave-local, verified R1 path) ----
  sq += __shfl_xor(sq, 16, 64);
  sq += __shfl_xor(sq, 32, 64);
  // C layout: row = quad*4 + v, col = ni*16 + l16
  float xs[4];
  #pragma unroll
  for (int v = 0; v < 4; ++v)
    xs[v] = __shfl(sq, quad * 4 + v, 64);

  float cs[16];
  #pragma unroll
  for (int ni = 0; ni < 16; ++ni) cs[ni] = csq[ni * 16 + l16];

  float rs[4] = {0.f, 0.f, 0.f, 0.f};
  #pragma unroll
  for (int ni = 0; ni < 16; ++ni) {
    #pragma unroll
    for (int v = 0; v < 4; ++v) {
      float d = xs[v] + cs[ni] - 2.0f * acc[ni][v];
      d = fmaxf(d, 0.f);
      float qv = __builtin_amdgcn_rcpf(1.0f + d);   // alpha=1: (1+d^2)^-1
      acc[ni][v] = qv;
      rs[v] += qv;
    }
  }
  #pragma unroll
  for (int v = 0; v < 4; ++v) {
    rs[v] += __shfl_xor(rs[v], 1, 64);
    rs[v] += __shfl_xor(rs[v], 2, 64);
    rs[v] += __shfl_xor(rs[v], 4, 64);
    rs[v] += __shfl_xor(rs[v], 8, 64);
    rs[v] = __builtin_amdgcn_rcpf(rs[v]);
  }
  #pragma unroll
  for (int v = 0; v < 4; ++v) {
    float* orow = out + (size_t)(row0 + w * 16 + quad * 4 + v) * K_CL;
    #pragma unroll
    for (int ni = 0; ni < 16; ++ni)
      orow[ni * 16 + l16] = acc[ni][v] * rs[v];
  }
}

extern "C" void kernel_launch(void* const* d_in, const int* in_sizes, int n_in,
                              void* d_out, int out_size, void* d_ws, size_t ws_size,
                              hipStream_t stream) {
  const float* x        = (const float*)d_in[0];
  const float* clusters = (const float*)d_in[1];
  float* out = (float*)d_out;
  const int N = in_sizes[0] / D_DIM;   // 65536

  u16*   cb  = (u16*)d_ws;                                    // 256*512*2 = 256 KB
  float* csq = (float*)((char*)d_ws + (size_t)K_CL * D_DIM * sizeof(u16));

  prep_kernel<<<K_CL, 128, 0, stream>>>(clusters, cb, csq);
  cluster_kernel<<<N / BM, 512, 0, stream>>>(x, cb, csq, out);
}